// Round 7
// baseline (144.797 us; speedup 1.0000x reference)
//
#include <hip/hip_runtime.h>
#include <hip/hip_bf16.h>

// out = v + 0.5*mask*(softmax_m(mem@v^T - 0.5*||mem||^2)^T @ mem - v)
//  k_prep  : memories f32 -> bf16 (memA, plain [m][d]) + row sumsq; v -> vbf
//  k_stage1: 512 WGs (256 thr) = 128 m-splits x 4 b-tiles, 16 chunks of 32 m.
//            32x32x16 MFMA. Pre-swizzled global_load_lds staging (round-5
//            verified), in-LDS transpose -> Tb (round-5 verified addressing,
//            2-way-bank thread mapping), in-lane softmax + defer-max,
//            lane-uniform rescale, register epilogue to part_o[s][dblk][b][4].
//  k_scale : per-b combine of split stats -> scale[s][b]
//  k_out   : dblk-parallel partial reduction + epilogue

#define NSPLIT 128
#define NCHUNK 16

typedef __attribute__((ext_vector_type(4))) float f32x4;
typedef __attribute__((ext_vector_type(16))) float f32x16;
typedef __attribute__((ext_vector_type(8))) short s16x8;
typedef __attribute__((ext_vector_type(2))) unsigned int u32x2;
typedef __attribute__((ext_vector_type(4))) unsigned int u32x4;

__device__ __forceinline__ unsigned short bf16rn(float f) {
  unsigned x = __builtin_bit_cast(unsigned, f);
  x += 0x7fffu + ((x >> 16) & 1u);
  return (unsigned short)(x >> 16);
}
__device__ __forceinline__ unsigned pk2(float a, float b) {
  return (unsigned)bf16rn(a) | ((unsigned)bf16rn(b) << 16);
}
__device__ __forceinline__ float bf2f(unsigned short u) {
  return __builtin_bit_cast(float, ((unsigned)u) << 16);
}

// Tb swizzle (128-B rows): spreads transpose-writes and PV reads across slots.
#define TSWZ(d) ((((d) ^ ((d) >> 3)) & 7) << 4)

// ---------------- kernel 0: prep (round-5 verified) ----------------
__global__ __launch_bounds__(512) void k_prep(const float* __restrict__ memg,
                                              const float* __restrict__ v,
                                              unsigned short* __restrict__ memA,
                                              unsigned short* __restrict__ vbf,
                                              float* __restrict__ msq) {
  const int wg = (int)blockIdx.x;
  const int tid = (int)threadIdx.x;
  const int w = tid >> 6, lane = tid & 63;
  if (wg < 256) {
    size_t m0 = (size_t)wg * 256 + w * 32;
#pragma unroll 4
    for (int i = 0; i < 32; ++i) {
      size_t m = m0 + i;
      f32x4 f = *reinterpret_cast<const f32x4*>(memg + m * 256 + lane * 4);
      u32x2 p;
      p[0] = pk2(f[0], f[1]);
      p[1] = pk2(f[2], f[3]);
      *reinterpret_cast<u32x2*>(memA + m * 256 + lane * 4) = p;
      float sq = f[0] * f[0] + f[1] * f[1] + f[2] * f[2] + f[3] * f[3];
#pragma unroll
      for (int s2 = 32; s2; s2 >>= 1) sq += __shfl_xor(sq, s2);
      if (lane == 0) msq[m] = sq;
    }
  } else {
    size_t base = (size_t)(wg - 256) * 8192 + (size_t)tid * 16;
#pragma unroll
    for (int i = 0; i < 4; ++i) {
      f32x4 f = *reinterpret_cast<const f32x4*>(v + base + i * 4);
      u32x2 p;
      p[0] = pk2(f[0], f[1]);
      p[1] = pk2(f[2], f[3]);
      *reinterpret_cast<u32x2*>(vbf + base + i * 4) = p;
    }
  }
}

// ---------------- kernel 1: split-M flash ----------------
__global__ __launch_bounds__(256) void k_stage1(
    const unsigned short* __restrict__ memA, const unsigned short* __restrict__ vbf,
    const float* __restrict__ msq, unsigned short* __restrict__ part_o,
    float* __restrict__ part_m, float* __restrict__ part_l) {
  __shared__ __align__(16) char lds[65536];  // Ab0 16K | Ab1 16K | Tb 32K
  char* const Ab0 = lds;
  char* const Ab1 = lds + 16384;
  char* const Tb = lds + 32768;

  const int tid = (int)threadIdx.x;
  const int w = tid >> 6;
  const int lane = tid & 63;
  const int hi = lane >> 5;
  const int c5 = lane & 31;

  // XCD grouping: 16 splits x 4 b-tiles per XCD.
  const int bid = (int)blockIdx.x;
  const int swz = (bid & 7) * 64 + (bid >> 3);
  const int s = swz >> 2;     // m-split 0..127
  const int btile = swz & 3;  // 0..3
  const int bw = btile * 128 + w * 32;
  const int b = bw + c5;

  // Pre-swizzled staging source (LDS dest linear): LDS[row][slot] holds
  // mem[row][slot ^ (row&7)] (16B slots). Round-5 verified form.
  const char* Ac = (const char*)memA;
  const size_t qsrc = (size_t)s * 262144 + (size_t)(tid >> 5) * 512 +
                      (size_t)(((tid & 31) ^ (tid >> 5)) * 16);

#define STAGE(bufp, t_)                                                          \
  do {                                                                           \
    _Pragma("unroll") for (int i_ = 0; i_ < 4; ++i_) {                           \
      __builtin_amdgcn_global_load_lds(                                          \
          (const __attribute__((address_space(1))) void*)(Ac + qsrc +            \
              (size_t)(t_) * 16384 + (size_t)i_ * 4096),                         \
          (__attribute__((address_space(3))) void*)((bufp) + w * 1024 + i_ * 4096), \
          16, 0, 0);                                                             \
    }                                                                            \
  } while (0)

  f32x16 acc[8];
#pragma unroll
  for (int n = 0; n < 8; ++n) acc[n] = (f32x16)0.0f;
  float rm = -__builtin_inff(), rs = 0.f;

  // v B-fragments: lane holds v[b][k*16 + hi*8 .. +7] for 16 ksteps
  s16x8 vr[16];
  STAGE(Ab0, 0);
#pragma unroll
  for (int k = 0; k < 16; ++k)
    vr[k] = *reinterpret_cast<const s16x8*>(vbf + (size_t)b * 256 + k * 16 + hi * 8);

  asm volatile("s_waitcnt vmcnt(0)" ::: "memory");
  __builtin_amdgcn_s_barrier();
  asm volatile("" ::: "memory");

  // transpose mapping: mbt = tid>>5 (4 m each), dbt = tid&31 (8 d each)
  const int mbt = tid >> 5;
  const int dbt = tid & 31;

  for (int t = 0; t < NCHUNK; ++t) {
    char* Abc = (t & 1) ? Ab1 : Ab0;
    char* Abn = (t & 1) ? Ab0 : Ab1;
    if (t < NCHUNK - 1) STAGE(Abn, t + 1);

    // ---- QK^T: S[32m][32b] = mem_chunk @ v^T ----
    const char* qb = Abc + c5 * 512;
    f32x16 S = (f32x16)0.0f;
    __builtin_amdgcn_s_setprio(1);
#pragma unroll
    for (int k = 0; k < 16; ++k) {
      s16x8 a = *reinterpret_cast<const s16x8*>(qb + ((k * 32 + hi * 16) ^ ((c5 & 7) << 4)));
      S = __builtin_amdgcn_mfma_f32_32x32x16_bf16(a, vr[k], S, 0, 0, 0);
    }
    __builtin_amdgcn_s_setprio(0);

    // ---- transpose Ab[cur] -> Tb (round-5 verified addressing) ----
    {
      u32x4 r0 = *reinterpret_cast<const u32x4*>(Abc + (mbt * 4 + 0) * 512 + ((dbt * 16) ^ (((mbt * 4 + 0) & 7) << 4)));
      u32x4 r1 = *reinterpret_cast<const u32x4*>(Abc + (mbt * 4 + 1) * 512 + ((dbt * 16) ^ (((mbt * 4 + 1) & 7) << 4)));
      u32x4 r2 = *reinterpret_cast<const u32x4*>(Abc + (mbt * 4 + 2) * 512 + ((dbt * 16) ^ (((mbt * 4 + 2) & 7) << 4)));
      u32x4 r3 = *reinterpret_cast<const u32x4*>(Abc + (mbt * 4 + 3) * 512 + ((dbt * 16) ^ (((mbt * 4 + 3) & 7) << 4)));
#pragma unroll
      for (int dd = 0; dd < 8; ++dd) {
        int sh = (dd & 1) * 16;
        unsigned h0 = (r0[dd >> 1] >> sh) & 0xffffu;
        unsigned h1 = (r1[dd >> 1] >> sh) & 0xffffu;
        unsigned h2 = (r2[dd >> 1] >> sh) & 0xffffu;
        unsigned h3 = (r3[dd >> 1] >> sh) & 0xffffu;
        u32x2 pw;
        pw[0] = h0 | (h1 << 16);
        pw[1] = h2 | (h3 << 16);
        int d = dbt * 8 + dd;
        *reinterpret_cast<u32x2*>(Tb + ((d * 128 + mbt * 8) ^ TSWZ(d))) = pw;
      }
    }
    asm volatile("s_waitcnt lgkmcnt(0)" ::: "memory");
    __builtin_amdgcn_s_barrier();
    asm volatile("" ::: "memory");

    // ---- bias: S row m = (reg&3) + 8*(reg>>2) + 4*hi ----
    const int mc = s * 512 + t * 32;
#pragma unroll
    for (int q = 0; q < 4; ++q) {
      f32x4 qq = *reinterpret_cast<const f32x4*>(msq + mc + 8 * q + 4 * hi);
#pragma unroll
      for (int r = 0; r < 4; ++r) S[4 * q + r] -= 0.5f * qq[r];
    }

    // ---- in-lane online softmax (col b = bw + c5), defer-max THR=8 ----
    float mx = S[0];
#pragma unroll
    for (int i = 1; i < 16; ++i) mx = fmaxf(mx, S[i]);
    mx = fmaxf(mx, __shfl_xor(mx, 32));
    if (!__all(mx <= rm + 8.0f)) {
      float nm = fmaxf(rm, mx);
      float al = __expf(rm - nm);
      rm = nm;
      rs *= al;
#pragma unroll
      for (int n = 0; n < 8; ++n) acc[n] *= al;
    }
    float ls = 0.f;
#pragma unroll
    for (int i = 0; i < 16; ++i) {
      float p = __expf(S[i] - rm);
      S[i] = p;
      ls += p;
    }
    ls += __shfl_xor(ls, 32);
    rs += ls;

    // ---- P -> B-fragments (desk-verified lane shuffle) ----
    unsigned pkd[8];
#pragma unroll
    for (int p = 0; p < 8; ++p) pkd[p] = pk2(S[2 * p], S[2 * p + 1]);
    s16x8 pb0, pb1;
#pragma unroll
    for (int kk = 0; kk < 2; ++kk) {
      u32x4 wv;
#pragma unroll
      for (int i = 0; i < 4; ++i) {
        const int src = (i >> 1) * 32 + c5;
        unsigned lo = (unsigned)__shfl((int)pkd[(i & 1) + 4 * kk], src);
        unsigned hv = (unsigned)__shfl((int)pkd[(i & 1) + 4 * kk + 2], src);
        wv[i] = hi ? hv : lo;
      }
      if (kk == 0) pb0 = __builtin_bit_cast(s16x8, wv);
      else         pb1 = __builtin_bit_cast(s16x8, wv);
    }

    // ---- PV: acc[d][b] += memT @ P (A = Tb rows, plain b128 reads) ----
    __builtin_amdgcn_s_setprio(1);
#pragma unroll
    for (int n = 0; n < 8; ++n) {
      const int d = n * 32 + c5;
      s16x8 bm0 = *reinterpret_cast<const s16x8*>(Tb + ((d * 128 + hi * 16) ^ TSWZ(d)));
      s16x8 bm1 = *reinterpret_cast<const s16x8*>(Tb + ((d * 128 + 32 + hi * 16) ^ TSWZ(d)));
      acc[n] = __builtin_amdgcn_mfma_f32_32x32x16_bf16(bm0, pb0, acc[n], 0, 0, 0);
      acc[n] = __builtin_amdgcn_mfma_f32_32x32x16_bf16(bm1, pb1, acc[n], 0, 0, 0);
    }
    __builtin_amdgcn_s_setprio(0);

    asm volatile("s_waitcnt vmcnt(0)" ::: "memory");
    __builtin_amdgcn_s_barrier();
    asm volatile("" ::: "memory");
  }

  // ---- stats [s][b] ----
  if (hi == 0) {
    part_m[(size_t)s * 512 + b] = rm;
    part_l[(size_t)s * 512 + b] = rs;
  }

  // ---- epilogue: direct coalesced stores, part_o[s][dblk(64)][b(512)][4] ----
  // acc lane layout: b = bw + c5, d = n*32 + 8q + 4hi + r  ->  dblk = n*8 + 2q + hi
#pragma unroll
  for (int n = 0; n < 8; ++n) {
#pragma unroll
    for (int q = 0; q < 4; ++q) {
      u32x2 pw;
      pw[0] = pk2(acc[n][4 * q + 0], acc[n][4 * q + 1]);
      pw[1] = pk2(acc[n][4 * q + 2], acc[n][4 * q + 3]);
      *reinterpret_cast<u32x2*>(part_o + (size_t)s * 131072 +
                                (size_t)(n * 8 + 2 * q + hi) * 2048 + (size_t)b * 4) = pw;
    }
  }
#undef STAGE
}

// ---------------- kernel 2: per-b stat combine -> scale[s][b] ----------------
__global__ __launch_bounds__(128) void k_scale(const float* __restrict__ part_m,
                                               const float* __restrict__ part_l,
                                               float* __restrict__ scale) {
  const int b = (int)blockIdx.x, t = (int)threadIdx.x;
  const int wv = t >> 6;
  __shared__ float red[4];
  float m = part_m[(size_t)t * 512 + b];
  float l = part_l[(size_t)t * 512 + b];
  float mm = m;
#pragma unroll
  for (int s2 = 32; s2; s2 >>= 1) mm = fmaxf(mm, __shfl_xor(mm, s2));
  if ((t & 63) == 0) red[wv] = mm;
  __syncthreads();
  float M = fmaxf(red[0], red[1]);
  float e = __expf(m - M);
  float z = e * l;
#pragma unroll
  for (int s2 = 32; s2; s2 >>= 1) z += __shfl_xor(z, s2);
  if ((t & 63) == 0) red[2 + wv] = z;
  __syncthreads();
  float Z = red[2] + red[3];
  scale[(size_t)t * 512 + b] = e / Z;
}

// ---------------- kernel 3: reduce partials + epilogue ----------------
__global__ __launch_bounds__(128) void k_out(const unsigned short* __restrict__ part_o,
                                             const float* __restrict__ scale,
                                             const float* __restrict__ v,
                                             const float* __restrict__ mask,
                                             float* __restrict__ out) {
  const int dblk = (int)blockIdx.x >> 2;              // 0..63
  const int b = ((int)blockIdx.x & 3) * 128 + (int)threadIdx.x;  // 0..511
  float a0 = 0.f, a1 = 0.f, a2 = 0.f, a3 = 0.f;
  const unsigned short* po = part_o + (size_t)dblk * 2048 + (size_t)b * 4;
#pragma unroll 8
  for (int gi = 0; gi < NSPLIT; ++gi) {
    u32x2 pw = *reinterpret_cast<const u32x2*>(po + (size_t)gi * 131072);
    float sc = scale[(size_t)gi * 512 + b];
    a0 = fmaf(sc, bf2f((unsigned short)pw[0]), a0);
    a1 = fmaf(sc, bf2f((unsigned short)(pw[0] >> 16)), a1);
    a2 = fmaf(sc, bf2f((unsigned short)pw[1]), a2);
    a3 = fmaf(sc, bf2f((unsigned short)(pw[1] >> 16)), a3);
  }
  const size_t idx = (size_t)b * 256 + (size_t)dblk * 4;
  f32x4 vv = *reinterpret_cast<const f32x4*>(v + idx);
  f32x4 mk = *reinterpret_cast<const f32x4*>(mask + idx);
  f32x4 o;
  o[0] = vv[0] + 0.5f * (a0 - vv[0]) * mk[0];
  o[1] = vv[1] + 0.5f * (a1 - vv[1]) * mk[1];
  o[2] = vv[2] + 0.5f * (a2 - vv[2]) * mk[2];
  o[3] = vv[3] + 0.5f * (a3 - vv[3]) * mk[3];
  *reinterpret_cast<f32x4*>(out + idx) = o;
}

extern "C" void kernel_launch(void* const* d_in, const int* in_sizes, int n_in,
                              void* d_out, int out_size, void* d_ws, size_t ws_size,
                              hipStream_t stream) {
  const float* v = (const float*)d_in[0];       // [512,256]
  const float* mask = (const float*)d_in[1];    // [512,256]
  const float* memg = (const float*)d_in[2];    // [65536,256]
  float* out = (float*)d_out;

  char* ws = (char*)d_ws;
  const size_t SZ_PO = (size_t)NSPLIT * 64 * 512 * 4 * 2;  // 32 MiB  [s][dblk][b][4] u16
  const size_t SZ_MA = (size_t)65536 * 256 * 2;            // 32 MiB
  const size_t SZ_MS = (size_t)65536 * 4;                  // 256 KiB
  const size_t SZ_VB = (size_t)512 * 256 * 2;              // 256 KiB
  const size_t SZ_ST = (size_t)NSPLIT * 512 * 4;           // 256 KiB
  unsigned short* part_o = (unsigned short*)ws;
  unsigned short* memA = (unsigned short*)(ws + SZ_PO);
  float* msq = (float*)(ws + SZ_PO + SZ_MA);
  unsigned short* vbf = (unsigned short*)(ws + SZ_PO + SZ_MA + SZ_MS);
  float* part_m = (float*)(ws + SZ_PO + SZ_MA + SZ_MS + SZ_VB);
  float* part_l = (float*)(ws + SZ_PO + SZ_MA + SZ_MS + SZ_VB + SZ_ST);
  float* scale = (float*)(ws + SZ_PO + SZ_MA + SZ_MS + SZ_VB + 2 * SZ_ST);

  k_prep<<<dim3(272), dim3(512), 0, stream>>>(memg, v, memA, vbf, msq);
  k_stage1<<<dim3(512), dim3(256), 0, stream>>>(memA, vbf, msq, part_o, part_m, part_l);
  k_scale<<<dim3(512), dim3(128), 0, stream>>>(part_m, part_l, scale);
  k_out<<<dim3(256), dim3(128), 0, stream>>>(part_o, scale, v, mask, out);
}

// Round 8
// 124.385 us; speedup vs baseline: 1.1641x; 1.1641x over previous
//
#include <hip/hip_runtime.h>
#include <hip/hip_bf16.h>

// out = v + 0.5*mask*(softmax_m(mem@v^T - 0.5*||mem||^2)^T @ mem - v)
//  k_prep  : memories f32 -> bf16 (memA [m][d]) + row sumsq; v -> vbf   (round-7 verbatim)
//  k_prepT : memA -> memTt tiled transpose image [m>>4][d][m&15] (LDS 32m-slab transpose)
//  k_stage1: 512 WGs (256 thr, launch_bounds(256,2)) = 128 m-splits x 4 b-tiles,
//            16 chunks of 32 m. 32x32x16 MFMA. QK: LDS-staged memA (pre-swizzled
//            global_load_lds, dbuf). PV: A-fragments read DIRECTLY from memTt
//            (coalesced 1KB loads, L1/L2-hit). No in-LDS transpose, one barrier
//            per chunk, LDS 32KB, regs <= 256 total -> 2 waves/SIMD.
//  k_scale : per-b combine of split stats -> scale[s][b]                (round-7 verbatim)
//  k_out   : dblk-parallel partial reduction + epilogue                 (round-7 verbatim)

#define NSPLIT 128
#define NCHUNK 16

typedef __attribute__((ext_vector_type(4))) float f32x4;
typedef __attribute__((ext_vector_type(16))) float f32x16;
typedef __attribute__((ext_vector_type(8))) short s16x8;
typedef __attribute__((ext_vector_type(2))) unsigned int u32x2;
typedef __attribute__((ext_vector_type(4))) unsigned int u32x4;

__device__ __forceinline__ unsigned short bf16rn(float f) {
  unsigned x = __builtin_bit_cast(unsigned, f);
  x += 0x7fffu + ((x >> 16) & 1u);
  return (unsigned short)(x >> 16);
}
__device__ __forceinline__ unsigned pk2(float a, float b) {
  return (unsigned)bf16rn(a) | ((unsigned)bf16rn(b) << 16);
}
__device__ __forceinline__ float bf2f(unsigned short u) {
  return __builtin_bit_cast(float, ((unsigned)u) << 16);
}

// ---------------- kernel 0: prep (round-7 verbatim) ----------------
__global__ __launch_bounds__(512) void k_prep(const float* __restrict__ memg,
                                              const float* __restrict__ v,
                                              unsigned short* __restrict__ memA,
                                              unsigned short* __restrict__ vbf,
                                              float* __restrict__ msq) {
  const int wg = (int)blockIdx.x;
  const int tid = (int)threadIdx.x;
  const int w = tid >> 6, lane = tid & 63;
  if (wg < 256) {
    size_t m0 = (size_t)wg * 256 + w * 32;
#pragma unroll 4
    for (int i = 0; i < 32; ++i) {
      size_t m = m0 + i;
      f32x4 f = *reinterpret_cast<const f32x4*>(memg + m * 256 + lane * 4);
      u32x2 p;
      p[0] = pk2(f[0], f[1]);
      p[1] = pk2(f[2], f[3]);
      *reinterpret_cast<u32x2*>(memA + m * 256 + lane * 4) = p;
      float sq = f[0] * f[0] + f[1] * f[1] + f[2] * f[2] + f[3] * f[3];
#pragma unroll
      for (int s2 = 32; s2; s2 >>= 1) sq += __shfl_xor(sq, s2);
      if (lane == 0) msq[m] = sq;
    }
  } else {
    size_t base = (size_t)(wg - 256) * 8192 + (size_t)tid * 16;
#pragma unroll
    for (int i = 0; i < 4; ++i) {
      f32x4 f = *reinterpret_cast<const f32x4*>(v + base + i * 4);
      u32x2 p;
      p[0] = pk2(f[0], f[1]);
      p[1] = pk2(f[2], f[3]);
      *reinterpret_cast<u32x2*>(vbf + base + i * 4) = p;
    }
  }
}

// ---------------- kernel 0b: build memTt[m>>4][d][m&15] from memA ----------------
__global__ __launch_bounds__(256) void k_prepT(const unsigned short* __restrict__ memA,
                                               unsigned short* __restrict__ memTt) {
  __shared__ __align__(16) char sl[32 * 528];
  const int t = (int)threadIdx.x;
  const int wg = (int)blockIdx.x;  // slab m0 = wg*32
  const int mm = t >> 3, dp = t & 7;
  const char* src = (const char*)memA + (((size_t)wg * 32 + mm) * 256 + (size_t)dp * 32) * 2;
#pragma unroll
  for (int j = 0; j < 4; ++j) {
    u32x4 vd = *reinterpret_cast<const u32x4*>(src + j * 16);
    *reinterpret_cast<u32x4*>(sl + mm * 528 + dp * 64 + j * 16) = vd;
  }
  __syncthreads();
#pragma unroll
  for (int h = 0; h < 2; ++h) {
    const int d = t;  // 0..255
    unsigned wbuf[8];
#pragma unroll
    for (int i = 0; i < 8; ++i) {
      unsigned lo = *reinterpret_cast<const unsigned short*>(sl + (h * 16 + 2 * i) * 528 + d * 2);
      unsigned hv = *reinterpret_cast<const unsigned short*>(sl + (h * 16 + 2 * i + 1) * 528 + d * 2);
      wbuf[i] = lo | (hv << 16);
    }
    char* dst = (char*)memTt + ((size_t)wg * 2 + h) * 8192 + (size_t)d * 32;
    u32x4 o0, o1;
    o0[0] = wbuf[0]; o0[1] = wbuf[1]; o0[2] = wbuf[2]; o0[3] = wbuf[3];
    o1[0] = wbuf[4]; o1[1] = wbuf[5]; o1[2] = wbuf[6]; o1[3] = wbuf[7];
    *reinterpret_cast<u32x4*>(dst) = o0;
    *reinterpret_cast<u32x4*>(dst + 16) = o1;
  }
}

// ---------------- kernel 1: split-M flash ----------------
__global__ __launch_bounds__(256, 2) void k_stage1(
    const unsigned short* __restrict__ memA, const unsigned short* __restrict__ memTt,
    const unsigned short* __restrict__ vbf, const float* __restrict__ msq,
    unsigned short* __restrict__ part_o, float* __restrict__ part_m,
    float* __restrict__ part_l) {
  __shared__ __align__(16) char lds[32768];  // Ab0 16K | Ab1 16K
  char* const Ab0 = lds;
  char* const Ab1 = lds + 16384;

  const int tid = (int)threadIdx.x;
  const int w = tid >> 6;
  const int lane = tid & 63;
  const int hi = lane >> 5;
  const int c5 = lane & 31;

  // XCD grouping: 16 splits x 4 b-tiles per XCD.
  const int bid = (int)blockIdx.x;
  const int swz = (bid & 7) * 64 + (bid >> 3);
  const int s = swz >> 2;     // m-split 0..127
  const int btile = swz & 3;  // 0..3
  const int bw = btile * 128 + w * 32;
  const int b = bw + c5;

  // Pre-swizzled staging source (LDS dest linear), round-5/7 verified form.
  const char* Ac = (const char*)memA;
  const size_t qsrc = (size_t)s * 262144 + (size_t)(tid >> 5) * 512 +
                      (size_t)(((tid & 31) ^ (tid >> 5)) * 16);

#define STAGE(bufp, t_)                                                          \
  do {                                                                           \
    _Pragma("unroll") for (int i_ = 0; i_ < 4; ++i_) {                           \
      __builtin_amdgcn_global_load_lds(                                          \
          (const __attribute__((address_space(1))) void*)(Ac + qsrc +            \
              (size_t)(t_) * 16384 + (size_t)i_ * 4096),                         \
          (__attribute__((address_space(3))) void*)((bufp) + w * 1024 + i_ * 4096), \
          16, 0, 0);                                                             \
    }                                                                            \
  } while (0)

  f32x16 acc[8];
#pragma unroll
  for (int n = 0; n < 8; ++n) acc[n] = (f32x16)0.0f;
  float rm = -__builtin_inff(), rs = 0.f;

  // v B-fragments: lane holds v[b][k*16 + hi*8 .. +7] for 16 ksteps
  s16x8 vr[16];
  STAGE(Ab0, 0);
#pragma unroll
  for (int k = 0; k < 16; ++k)
    vr[k] = *reinterpret_cast<const s16x8*>(vbf + (size_t)b * 256 + k * 16 + hi * 8);

  asm volatile("s_waitcnt vmcnt(0)" ::: "memory");
  __builtin_amdgcn_s_barrier();
  asm volatile("" ::: "memory");

  for (int t = 0; t < NCHUNK; ++t) {
    char* Abc = (t & 1) ? Ab1 : Ab0;
    char* Abn = (t & 1) ? Ab0 : Ab1;
    if (t < NCHUNK - 1) STAGE(Abn, t + 1);

    // PV A-source for this chunk (global, tiled transpose image)
    const char* tb = (const char*)memTt + ((size_t)s * 32 + (size_t)t * 2) * 8192;

    // ---- QK^T: S[32m][32b], two accumulation chains ----
    const char* qb = Abc + c5 * 512;
    f32x16 Sa = (f32x16)0.0f, Sb = (f32x16)0.0f;
    __builtin_amdgcn_s_setprio(1);
#pragma unroll
    for (int k = 0; k < 16; k += 2) {
      s16x8 a0 = *reinterpret_cast<const s16x8*>(qb + ((k * 32 + hi * 16) ^ ((c5 & 7) << 4)));
      s16x8 a1 = *reinterpret_cast<const s16x8*>(qb + (((k + 1) * 32 + hi * 16) ^ ((c5 & 7) << 4)));
      Sa = __builtin_amdgcn_mfma_f32_32x32x16_bf16(a0, vr[k], Sa, 0, 0, 0);
      Sb = __builtin_amdgcn_mfma_f32_32x32x16_bf16(a1, vr[k + 1], Sb, 0, 0, 0);
    }
    __builtin_amdgcn_s_setprio(0);
    f32x16 S = Sa + Sb;

    // ---- bias: S row m = (reg&3) + 8*(reg>>2) + 4*hi ----
    const int mc = s * 512 + t * 32;
#pragma unroll
    for (int q = 0; q < 4; ++q) {
      f32x4 qq = *reinterpret_cast<const f32x4*>(msq + mc + 8 * q + 4 * hi);
#pragma unroll
      for (int r = 0; r < 4; ++r) S[4 * q + r] -= 0.5f * qq[r];
    }

    // ---- in-lane online softmax (col b = bw + c5), defer-max THR=8 ----
    float mx = S[0];
#pragma unroll
    for (int i = 1; i < 16; ++i) mx = fmaxf(mx, S[i]);
    mx = fmaxf(mx, __shfl_xor(mx, 32));
    if (!__all(mx <= rm + 8.0f)) {
      float nm = fmaxf(rm, mx);
      float al = __expf(rm - nm);
      rm = nm;
      rs *= al;
#pragma unroll
      for (int n = 0; n < 8; ++n) acc[n] *= al;
    }
    float ls = 0.f;
#pragma unroll
    for (int i = 0; i < 16; ++i) {
      float p = __expf(S[i] - rm);
      S[i] = p;
      ls += p;
    }
    ls += __shfl_xor(ls, 32);
    rs += ls;

    // ---- P -> B-fragments (round-7 verified lane shuffle) ----
    unsigned pkd[8];
#pragma unroll
    for (int p = 0; p < 8; ++p) pkd[p] = pk2(S[2 * p], S[2 * p + 1]);
    s16x8 pb0, pb1;
#pragma unroll
    for (int kk = 0; kk < 2; ++kk) {
      u32x4 wv;
#pragma unroll
      for (int i = 0; i < 4; ++i) {
        const int src = (i >> 1) * 32 + c5;
        unsigned lo = (unsigned)__shfl((int)pkd[(i & 1) + 4 * kk], src);
        unsigned hv = (unsigned)__shfl((int)pkd[(i & 1) + 4 * kk + 2], src);
        wv[i] = hi ? hv : lo;
      }
      if (kk == 0) pb0 = __builtin_bit_cast(s16x8, wv);
      else         pb1 = __builtin_bit_cast(s16x8, wv);
    }

    // ---- PV: acc[d][b] += memT @ P (A = coalesced global reads of memTt) ----
    __builtin_amdgcn_s_setprio(1);
#pragma unroll
    for (int n = 0; n < 8; ++n) {
      const char* ta = tb + n * 1024 + c5 * 32 + hi * 16;
      s16x8 bm0 = *reinterpret_cast<const s16x8*>(ta);
      s16x8 bm1 = *reinterpret_cast<const s16x8*>(ta + 8192);
      acc[n] = __builtin_amdgcn_mfma_f32_32x32x16_bf16(bm0, pb0, acc[n], 0, 0, 0);
      acc[n] = __builtin_amdgcn_mfma_f32_32x32x16_bf16(bm1, pb1, acc[n], 0, 0, 0);
    }
    __builtin_amdgcn_s_setprio(0);

    asm volatile("s_waitcnt vmcnt(0)" ::: "memory");
    __builtin_amdgcn_s_barrier();
    asm volatile("" ::: "memory");
  }

  // ---- stats [s][b] ----
  if (hi == 0) {
    part_m[(size_t)s * 512 + b] = rm;
    part_l[(size_t)s * 512 + b] = rs;
  }

  // ---- epilogue: direct coalesced stores, part_o[s][dblk(64)][b(512)][4] ----
  // acc lane layout: b = bw + c5, d = n*32 + 8q + 4hi + r  ->  dblk = n*8 + 2q + hi
#pragma unroll
  for (int n = 0; n < 8; ++n) {
#pragma unroll
    for (int q = 0; q < 4; ++q) {
      u32x2 pw;
      pw[0] = pk2(acc[n][4 * q + 0], acc[n][4 * q + 1]);
      pw[1] = pk2(acc[n][4 * q + 2], acc[n][4 * q + 3]);
      *reinterpret_cast<u32x2*>(part_o + (size_t)s * 131072 +
                                (size_t)(n * 8 + 2 * q + hi) * 2048 + (size_t)b * 4) = pw;
    }
  }
#undef STAGE
}

// ---------------- kernel 2: per-b stat combine -> scale[s][b] (round-7 verbatim) ----------------
__global__ __launch_bounds__(128) void k_scale(const float* __restrict__ part_m,
                                               const float* __restrict__ part_l,
                                               float* __restrict__ scale) {
  const int b = (int)blockIdx.x, t = (int)threadIdx.x;
  const int wv = t >> 6;
  __shared__ float red[4];
  float m = part_m[(size_t)t * 512 + b];
  float l = part_l[(size_t)t * 512 + b];
  float mm = m;
#pragma unroll
  for (int s2 = 32; s2; s2 >>= 1) mm = fmaxf(mm, __shfl_xor(mm, s2));
  if ((t & 63) == 0) red[wv] = mm;
  __syncthreads();
  float M = fmaxf(red[0], red[1]);
  float e = __expf(m - M);
  float z = e * l;
#pragma unroll
  for (int s2 = 32; s2; s2 >>= 1) z += __shfl_xor(z, s2);
  if ((t & 63) == 0) red[2 + wv] = z;
  __syncthreads();
  float Z = red[2] + red[3];
  scale[(size_t)t * 512 + b] = e / Z;
}

// ---------------- kernel 3: reduce partials + epilogue (round-7 verbatim) ----------------
__global__ __launch_bounds__(128) void k_out(const unsigned short* __restrict__ part_o,
                                             const float* __restrict__ scale,
                                             const float* __restrict__ v,
                                             const float* __restrict__ mask,
                                             float* __restrict__ out) {
  const int dblk = (int)blockIdx.x >> 2;                         // 0..63
  const int b = ((int)blockIdx.x & 3) * 128 + (int)threadIdx.x;  // 0..511
  float a0 = 0.f, a1 = 0.f, a2 = 0.f, a3 = 0.f;
  const unsigned short* po = part_o + (size_t)dblk * 2048 + (size_t)b * 4;
#pragma unroll 8
  for (int gi = 0; gi < NSPLIT; ++gi) {
    u32x2 pw = *reinterpret_cast<const u32x2*>(po + (size_t)gi * 131072);
    float sc = scale[(size_t)gi * 512 + b];
    a0 = fmaf(sc, bf2f((unsigned short)pw[0]), a0);
    a1 = fmaf(sc, bf2f((unsigned short)(pw[0] >> 16)), a1);
    a2 = fmaf(sc, bf2f((unsigned short)pw[1]), a2);
    a3 = fmaf(sc, bf2f((unsigned short)(pw[1] >> 16)), a3);
  }
  const size_t idx = (size_t)b * 256 + (size_t)dblk * 4;
  f32x4 vv = *reinterpret_cast<const f32x4*>(v + idx);
  f32x4 mk = *reinterpret_cast<const f32x4*>(mask + idx);
  f32x4 o;
  o[0] = vv[0] + 0.5f * (a0 - vv[0]) * mk[0];
  o[1] = vv[1] + 0.5f * (a1 - vv[1]) * mk[1];
  o[2] = vv[2] + 0.5f * (a2 - vv[2]) * mk[2];
  o[3] = vv[3] + 0.5f * (a3 - vv[3]) * mk[3];
  *reinterpret_cast<f32x4*>(out + idx) = o;
}

extern "C" void kernel_launch(void* const* d_in, const int* in_sizes, int n_in,
                              void* d_out, int out_size, void* d_ws, size_t ws_size,
                              hipStream_t stream) {
  const float* v = (const float*)d_in[0];       // [512,256]
  const float* mask = (const float*)d_in[1];    // [512,256]
  const float* memg = (const float*)d_in[2];    // [65536,256]
  float* out = (float*)d_out;

  char* ws = (char*)d_ws;
  const size_t SZ_PO = (size_t)NSPLIT * 64 * 512 * 4 * 2;  // 32 MiB  [s][dblk][b][4] u16
  const size_t SZ_MA = (size_t)65536 * 256 * 2;            // 32 MiB
  const size_t SZ_MS = (size_t)65536 * 4;                  // 256 KiB
  const size_t SZ_VB = (size_t)512 * 256 * 2;              // 256 KiB
  const size_t SZ_ST = (size_t)NSPLIT * 512 * 4;           // 256 KiB
  unsigned short* part_o = (unsigned short*)ws;
  unsigned short* memA = (unsigned short*)(ws + SZ_PO);
  float* msq = (float*)(ws + SZ_PO + SZ_MA);
  unsigned short* vbf = (unsigned short*)(ws + SZ_PO + SZ_MA + SZ_MS);
  float* part_m = (float*)(ws + SZ_PO + SZ_MA + SZ_MS + SZ_VB);
  float* part_l = (float*)(ws + SZ_PO + SZ_MA + SZ_MS + SZ_VB + SZ_ST);
  float* scale = (float*)(ws + SZ_PO + SZ_MA + SZ_MS + SZ_VB + 2 * SZ_ST);
  unsigned short* memTt = (unsigned short*)(ws + SZ_PO + SZ_MA + SZ_MS + SZ_VB + 3 * SZ_ST);

  k_prep<<<dim3(272), dim3(512), 0, stream>>>(memg, v, memA, vbf, msq);
  k_prepT<<<dim3(2048), dim3(256), 0, stream>>>(memA, memTt);
  k_stage1<<<dim3(512), dim3(256), 0, stream>>>(memA, memTt, vbf, msq, part_o, part_m, part_l);
  k_scale<<<dim3(512), dim3(128), 0, stream>>>(part_m, part_l, scale);
  k_out<<<dim3(256), dim3(128), 0, stream>>>(part_o, scale, v, mask, out);
}

// Round 9
// 108.067 us; speedup vs baseline: 1.3399x; 1.1510x over previous
//
#include <hip/hip_runtime.h>
#include <hip/hip_bf16.h>

// out = v + 0.5*mask*(softmax_m(mem@v^T - 0.5*||mem||^2)^T @ mem - v)
//  k_prep  : memories f32 -> bf16 (memA [m][d]) + row sumsq; v -> vbf   (verified)
//  k_prepT : memA -> memTt tiled transpose image [m>>4][d][m&15]        (verified r8)
//  k_stage1: 512 WGs (256 thr, lb(256,2)) = 128 m-splits x 4 b-tiles, 16 chunks
//            of 32 m. 32x32x16 MFMA. BOTH operand images (memA for QK, memTt for
//            PV) staged to LDS via dbuf global_load_lds; PV LDS reads swizzled
//            (bit4 ^= bit8) with inverse-swizzled global source. One barrier
//            per chunk. In-lane softmax + defer-max, lane-uniform rescale,
//            register epilogue to part_o[s][dblk][b][4].
//  k_scale : per-b combine of split stats -> scale[s][b]                (verified)
//  k_out   : dblk-parallel partial reduction + epilogue                 (verified)

#define NSPLIT 128
#define NCHUNK 16

typedef __attribute__((ext_vector_type(4))) float f32x4;
typedef __attribute__((ext_vector_type(16))) float f32x16;
typedef __attribute__((ext_vector_type(8))) short s16x8;
typedef __attribute__((ext_vector_type(2))) unsigned int u32x2;
typedef __attribute__((ext_vector_type(4))) unsigned int u32x4;

__device__ __forceinline__ unsigned short bf16rn(float f) {
  unsigned x = __builtin_bit_cast(unsigned, f);
  x += 0x7fffu + ((x >> 16) & 1u);
  return (unsigned short)(x >> 16);
}
__device__ __forceinline__ unsigned pk2(float a, float b) {
  return (unsigned)bf16rn(a) | ((unsigned)bf16rn(b) << 16);
}
__device__ __forceinline__ float bf2f(unsigned short u) {
  return __builtin_bit_cast(float, ((unsigned)u) << 16);
}

// ---------------- kernel 0: prep (verified verbatim) ----------------
__global__ __launch_bounds__(512) void k_prep(const float* __restrict__ memg,
                                              const float* __restrict__ v,
                                              unsigned short* __restrict__ memA,
                                              unsigned short* __restrict__ vbf,
                                              float* __restrict__ msq) {
  const int wg = (int)blockIdx.x;
  const int tid = (int)threadIdx.x;
  const int w = tid >> 6, lane = tid & 63;
  if (wg < 256) {
    size_t m0 = (size_t)wg * 256 + w * 32;
#pragma unroll 4
    for (int i = 0; i < 32; ++i) {
      size_t m = m0 + i;
      f32x4 f = *reinterpret_cast<const f32x4*>(memg + m * 256 + lane * 4);
      u32x2 p;
      p[0] = pk2(f[0], f[1]);
      p[1] = pk2(f[2], f[3]);
      *reinterpret_cast<u32x2*>(memA + m * 256 + lane * 4) = p;
      float sq = f[0] * f[0] + f[1] * f[1] + f[2] * f[2] + f[3] * f[3];
#pragma unroll
      for (int s2 = 32; s2; s2 >>= 1) sq += __shfl_xor(sq, s2);
      if (lane == 0) msq[m] = sq;
    }
  } else {
    size_t base = (size_t)(wg - 256) * 8192 + (size_t)tid * 16;
#pragma unroll
    for (int i = 0; i < 4; ++i) {
      f32x4 f = *reinterpret_cast<const f32x4*>(v + base + i * 4);
      u32x2 p;
      p[0] = pk2(f[0], f[1]);
      p[1] = pk2(f[2], f[3]);
      *reinterpret_cast<u32x2*>(vbf + base + i * 4) = p;
    }
  }
}

// ---------------- kernel 0b: memTt[m>>4][d][m&15] (verified r8 verbatim) ----------------
__global__ __launch_bounds__(256) void k_prepT(const unsigned short* __restrict__ memA,
                                               unsigned short* __restrict__ memTt) {
  __shared__ __align__(16) char sl[32 * 528];
  const int t = (int)threadIdx.x;
  const int wg = (int)blockIdx.x;  // slab m0 = wg*32
  const int mm = t >> 3, dp = t & 7;
  const char* src = (const char*)memA + (((size_t)wg * 32 + mm) * 256 + (size_t)dp * 32) * 2;
#pragma unroll
  for (int j = 0; j < 4; ++j) {
    u32x4 vd = *reinterpret_cast<const u32x4*>(src + j * 16);
    *reinterpret_cast<u32x4*>(sl + mm * 528 + dp * 64 + j * 16) = vd;
  }
  __syncthreads();
#pragma unroll
  for (int h = 0; h < 2; ++h) {
    const int d = t;  // 0..255
    unsigned wbuf[8];
#pragma unroll
    for (int i = 0; i < 8; ++i) {
      unsigned lo = *reinterpret_cast<const unsigned short*>(sl + (h * 16 + 2 * i) * 528 + d * 2);
      unsigned hv = *reinterpret_cast<const unsigned short*>(sl + (h * 16 + 2 * i + 1) * 528 + d * 2);
      wbuf[i] = lo | (hv << 16);
    }
    char* dst = (char*)memTt + ((size_t)wg * 2 + h) * 8192 + (size_t)d * 32;
    u32x4 o0, o1;
    o0[0] = wbuf[0]; o0[1] = wbuf[1]; o0[2] = wbuf[2]; o0[3] = wbuf[3];
    o1[0] = wbuf[4]; o1[1] = wbuf[5]; o1[2] = wbuf[6]; o1[3] = wbuf[7];
    *reinterpret_cast<u32x4*>(dst) = o0;
    *reinterpret_cast<u32x4*>(dst + 16) = o1;
  }
}

// ---------------- kernel 1: split-M flash ----------------
__global__ __launch_bounds__(256, 2) void k_stage1(
    const unsigned short* __restrict__ memA, const unsigned short* __restrict__ memTt,
    const unsigned short* __restrict__ vbf, const float* __restrict__ msq,
    unsigned short* __restrict__ part_o, float* __restrict__ part_m,
    float* __restrict__ part_l) {
  __shared__ __align__(16) char lds[65536];  // Ab0 16K | Ab1 16K | Tt0 16K | Tt1 16K
  char* const Ab0 = lds;
  char* const Ab1 = lds + 16384;
  char* const Tt0 = lds + 32768;
  char* const Tt1 = lds + 49152;

  const int tid = (int)threadIdx.x;
  const int w = tid >> 6;
  const int lane = tid & 63;
  const int hi = lane >> 5;
  const int c5 = lane & 31;

  // XCD grouping: 16 splits x 4 b-tiles per XCD.
  const int bid = (int)blockIdx.x;
  const int swz = (bid & 7) * 64 + (bid >> 3);
  const int s = swz >> 2;     // m-split 0..127
  const int btile = swz & 3;  // 0..3
  const int bw = btile * 128 + w * 32;
  const int b = bw + c5;

  // QK staging source (pre-swizzled; verified r5/7/8 form)
  const char* Ac = (const char*)memA;
  const size_t qsrc = (size_t)s * 262144 + (size_t)(tid >> 5) * 512 +
                      (size_t)(((tid & 31) ^ (tid >> 5)) * 16);
  // PV staging source: LDS linear, source carries the read-swizzle involution
  // f(x) = x ^ ((bit8(x))<<4); bit8(z) = lane bit4 -> offset (lane*16)^(lane&16).
  const char* Tc = (const char*)memTt;
  const size_t tsrc = (size_t)s * 262144 + (size_t)w * 1024 +
                      (size_t)(((unsigned)lane * 16u) ^ ((unsigned)lane & 16u));

#define STAGE_A(bufp, t_)                                                        \
  do {                                                                           \
    _Pragma("unroll") for (int i_ = 0; i_ < 4; ++i_) {                           \
      __builtin_amdgcn_global_load_lds(                                          \
          (const __attribute__((address_space(1))) void*)(Ac + qsrc +            \
              (size_t)(t_) * 16384 + (size_t)i_ * 4096),                         \
          (__attribute__((address_space(3))) void*)((bufp) + w * 1024 + i_ * 4096), \
          16, 0, 0);                                                             \
    }                                                                            \
  } while (0)
#define STAGE_T(bufp, t_)                                                        \
  do {                                                                           \
    _Pragma("unroll") for (int i_ = 0; i_ < 4; ++i_) {                           \
      __builtin_amdgcn_global_load_lds(                                          \
          (const __attribute__((address_space(1))) void*)(Tc + tsrc +            \
              (size_t)(t_) * 16384 + (size_t)i_ * 4096),                         \
          (__attribute__((address_space(3))) void*)((bufp) + w * 1024 + i_ * 4096), \
          16, 0, 0);                                                             \
    }                                                                            \
  } while (0)

  f32x16 acc[8];
#pragma unroll
  for (int n = 0; n < 8; ++n) acc[n] = (f32x16)0.0f;
  float rm = -__builtin_inff(), rs = 0.f;

  // v B-fragments: lane holds v[b][k*16 + hi*8 .. +7] for 16 ksteps
  s16x8 vr[16];
  STAGE_A(Ab0, 0);
  STAGE_T(Tt0, 0);
#pragma unroll
  for (int k = 0; k < 16; ++k)
    vr[k] = *reinterpret_cast<const s16x8*>(vbf + (size_t)b * 256 + k * 16 + hi * 8);

  asm volatile("s_waitcnt vmcnt(0)" ::: "memory");
  __builtin_amdgcn_s_barrier();
  asm volatile("" ::: "memory");

  for (int t = 0; t < NCHUNK; ++t) {
    char* Abc = (t & 1) ? Ab1 : Ab0;
    char* Abn = (t & 1) ? Ab0 : Ab1;
    char* Ttc = (t & 1) ? Tt1 : Tt0;
    char* Ttn = (t & 1) ? Tt0 : Tt1;
    if (t < NCHUNK - 1) {
      STAGE_A(Abn, t + 1);
      STAGE_T(Ttn, t + 1);
    }

    // ---- QK^T: S[32m][32b], two accumulation chains ----
    const char* qb = Abc + c5 * 512;
    f32x16 Sa = (f32x16)0.0f, Sb = (f32x16)0.0f;
    __builtin_amdgcn_s_setprio(1);
#pragma unroll
    for (int k = 0; k < 16; k += 2) {
      s16x8 a0 = *reinterpret_cast<const s16x8*>(qb + ((k * 32 + hi * 16) ^ ((c5 & 7) << 4)));
      s16x8 a1 = *reinterpret_cast<const s16x8*>(qb + (((k + 1) * 32 + hi * 16) ^ ((c5 & 7) << 4)));
      Sa = __builtin_amdgcn_mfma_f32_32x32x16_bf16(a0, vr[k], Sa, 0, 0, 0);
      Sb = __builtin_amdgcn_mfma_f32_32x32x16_bf16(a1, vr[k + 1], Sb, 0, 0, 0);
    }
    __builtin_amdgcn_s_setprio(0);
    f32x16 S = Sa + Sb;

    // ---- bias: S row m = (reg&3) + 8*(reg>>2) + 4*hi ----
    const int mc = s * 512 + t * 32;
#pragma unroll
    for (int q = 0; q < 4; ++q) {
      f32x4 qq = *reinterpret_cast<const f32x4*>(msq + mc + 8 * q + 4 * hi);
#pragma unroll
      for (int r = 0; r < 4; ++r) S[4 * q + r] -= 0.5f * qq[r];
    }

    // ---- in-lane online softmax (col b = bw + c5), defer-max THR=8 ----
    float mx = S[0];
#pragma unroll
    for (int i = 1; i < 16; ++i) mx = fmaxf(mx, S[i]);
    mx = fmaxf(mx, __shfl_xor(mx, 32));
    if (!__all(mx <= rm + 8.0f)) {
      float nm = fmaxf(rm, mx);
      float al = __expf(rm - nm);
      rm = nm;
      rs *= al;
#pragma unroll
      for (int n = 0; n < 8; ++n) acc[n] *= al;
    }
    float ls = 0.f;
#pragma unroll
    for (int i = 0; i < 16; ++i) {
      float p = __expf(S[i] - rm);
      S[i] = p;
      ls += p;
    }
    ls += __shfl_xor(ls, 32);
    rs += ls;

    // ---- P -> B-fragments (verified lane shuffle) ----
    unsigned pkd[8];
#pragma unroll
    for (int p = 0; p < 8; ++p) pkd[p] = pk2(S[2 * p], S[2 * p + 1]);
    s16x8 pb0, pb1;
#pragma unroll
    for (int kk = 0; kk < 2; ++kk) {
      u32x4 wv;
#pragma unroll
      for (int i = 0; i < 4; ++i) {
        const int src = (i >> 1) * 32 + c5;
        unsigned lo = (unsigned)__shfl((int)pkd[(i & 1) + 4 * kk], src);
        unsigned hv = (unsigned)__shfl((int)pkd[(i & 1) + 4 * kk + 2], src);
        wv[i] = hi ? hv : lo;
      }
      if (kk == 0) pb0 = __builtin_bit_cast(s16x8, wv);
      else         pb1 = __builtin_bit_cast(s16x8, wv);
    }

    // ---- PV: acc[d][b] += memT @ P (A = LDS Tt, swizzled reads) ----
    __builtin_amdgcn_s_setprio(1);
#pragma unroll
    for (int n = 0; n < 8; ++n) {
      const int ro = n * 1024 + c5 * 32 + ((hi * 16) ^ ((c5 & 8) << 1));
      s16x8 bm0 = *reinterpret_cast<const s16x8*>(Ttc + ro);
      s16x8 bm1 = *reinterpret_cast<const s16x8*>(Ttc + ro + 8192);
      acc[n] = __builtin_amdgcn_mfma_f32_32x32x16_bf16(bm0, pb0, acc[n], 0, 0, 0);
      acc[n] = __builtin_amdgcn_mfma_f32_32x32x16_bf16(bm1, pb1, acc[n], 0, 0, 0);
    }
    __builtin_amdgcn_s_setprio(0);

    asm volatile("s_waitcnt vmcnt(0)" ::: "memory");
    __builtin_amdgcn_s_barrier();
    asm volatile("" ::: "memory");
  }

  // ---- stats [s][b] ----
  if (hi == 0) {
    part_m[(size_t)s * 512 + b] = rm;
    part_l[(size_t)s * 512 + b] = rs;
  }

  // ---- epilogue: direct coalesced stores, part_o[s][dblk(64)][b(512)][4] ----
  // acc lane layout: b = bw + c5, d = n*32 + 8q + 4hi + r  ->  dblk = n*8 + 2q + hi
#pragma unroll
  for (int n = 0; n < 8; ++n) {
#pragma unroll
    for (int q = 0; q < 4; ++q) {
      u32x2 pw;
      pw[0] = pk2(acc[n][4 * q + 0], acc[n][4 * q + 1]);
      pw[1] = pk2(acc[n][4 * q + 2], acc[n][4 * q + 3]);
      *reinterpret_cast<u32x2*>(part_o + (size_t)s * 131072 +
                                (size_t)(n * 8 + 2 * q + hi) * 2048 + (size_t)b * 4) = pw;
    }
  }
#undef STAGE_A
#undef STAGE_T
}

// ---------------- kernel 2: per-b stat combine -> scale[s][b] (verified) ----------------
__global__ __launch_bounds__(128) void k_scale(const float* __restrict__ part_m,
                                               const float* __restrict__ part_l,
                                               float* __restrict__ scale) {
  const int b = (int)blockIdx.x, t = (int)threadIdx.x;
  const int wv = t >> 6;
  __shared__ float red[4];
  float m = part_m[(size_t)t * 512 + b];
  float l = part_l[(size_t)t * 512 + b];
  float mm = m;
#pragma unroll
  for (int s2 = 32; s2; s2 >>= 1) mm = fmaxf(mm, __shfl_xor(mm, s2));
  if ((t & 63) == 0) red[wv] = mm;
  __syncthreads();
  float M = fmaxf(red[0], red[1]);
  float e = __expf(m - M);
  float z = e * l;
#pragma unroll
  for (int s2 = 32; s2; s2 >>= 1) z += __shfl_xor(z, s2);
  if ((t & 63) == 0) red[2 + wv] = z;
  __syncthreads();
  float Z = red[2] + red[3];
  scale[(size_t)t * 512 + b] = e / Z;
}

// ---------------- kernel 3: reduce partials + epilogue (verified) ----------------
__global__ __launch_bounds__(128) void k_out(const unsigned short* __restrict__ part_o,
                                             const float* __restrict__ scale,
                                             const float* __restrict__ v,
                                             const float* __restrict__ mask,
                                             float* __restrict__ out) {
  const int dblk = (int)blockIdx.x >> 2;                         // 0..63
  const int b = ((int)blockIdx.x & 3) * 128 + (int)threadIdx.x;  // 0..511
  float a0 = 0.f, a1 = 0.f, a2 = 0.f, a3 = 0.f;
  const unsigned short* po = part_o + (size_t)dblk * 2048 + (size_t)b * 4;
#pragma unroll 8
  for (int gi = 0; gi < NSPLIT; ++gi) {
    u32x2 pw = *reinterpret_cast<const u32x2*>(po + (size_t)gi * 131072);
    float sc = scale[(size_t)gi * 512 + b];
    a0 = fmaf(sc, bf2f((unsigned short)pw[0]), a0);
    a1 = fmaf(sc, bf2f((unsigned short)(pw[0] >> 16)), a1);
    a2 = fmaf(sc, bf2f((unsigned short)pw[1]), a2);
    a3 = fmaf(sc, bf2f((unsigned short)(pw[1] >> 16)), a3);
  }
  const size_t idx = (size_t)b * 256 + (size_t)dblk * 4;
  f32x4 vv = *reinterpret_cast<const f32x4*>(v + idx);
  f32x4 mk = *reinterpret_cast<const f32x4*>(mask + idx);
  f32x4 o;
  o[0] = vv[0] + 0.5f * (a0 - vv[0]) * mk[0];
  o[1] = vv[1] + 0.5f * (a1 - vv[1]) * mk[1];
  o[2] = vv[2] + 0.5f * (a2 - vv[2]) * mk[2];
  o[3] = vv[3] + 0.5f * (a3 - vv[3]) * mk[3];
  *reinterpret_cast<f32x4*>(out + idx) = o;
}

extern "C" void kernel_launch(void* const* d_in, const int* in_sizes, int n_in,
                              void* d_out, int out_size, void* d_ws, size_t ws_size,
                              hipStream_t stream) {
  const float* v = (const float*)d_in[0];       // [512,256]
  const float* mask = (const float*)d_in[1];    // [512,256]
  const float* memg = (const float*)d_in[2];    // [65536,256]
  float* out = (float*)d_out;

  char* ws = (char*)d_ws;
  const size_t SZ_PO = (size_t)NSPLIT * 64 * 512 * 4 * 2;  // 32 MiB  [s][dblk][b][4] u16
  const size_t SZ_MA = (size_t)65536 * 256 * 2;            // 32 MiB
  const size_t SZ_MS = (size_t)65536 * 4;                  // 256 KiB
  const size_t SZ_VB = (size_t)512 * 256 * 2;              // 256 KiB
  const size_t SZ_ST = (size_t)NSPLIT * 512 * 4;           // 256 KiB
  unsigned short* part_o = (unsigned short*)ws;
  unsigned short* memA = (unsigned short*)(ws + SZ_PO);
  float* msq = (float*)(ws + SZ_PO + SZ_MA);
  unsigned short* vbf = (unsigned short*)(ws + SZ_PO + SZ_MA + SZ_MS);
  float* part_m = (float*)(ws + SZ_PO + SZ_MA + SZ_MS + SZ_VB);
  float* part_l = (float*)(ws + SZ_PO + SZ_MA + SZ_MS + SZ_VB + SZ_ST);
  float* scale = (float*)(ws + SZ_PO + SZ_MA + SZ_MS + SZ_VB + 2 * SZ_ST);
  unsigned short* memTt = (unsigned short*)(ws + SZ_PO + SZ_MA + SZ_MS + SZ_VB + 3 * SZ_ST);

  k_prep<<<dim3(272), dim3(512), 0, stream>>>(memg, v, memA, vbf, msq);
  k_prepT<<<dim3(2048), dim3(256), 0, stream>>>(memA, memTt);
  k_stage1<<<dim3(512), dim3(256), 0, stream>>>(memA, memTt, vbf, msq, part_o, part_m, part_l);
  k_scale<<<dim3(512), dim3(128), 0, stream>>>(part_m, part_l, scale);
  k_out<<<dim3(256), dim3(128), 0, stream>>>(part_o, scale, v, mask, out);
}

// Round 10
// 107.660 us; speedup vs baseline: 1.3450x; 1.0038x over previous
//
#include <hip/hip_runtime.h>
#include <hip/hip_bf16.h>

// out = v + 0.5*mask*(softmax_m(mem@v^T - 0.5*||mem||^2)^T @ mem - v)
//  k_prep  : memories f32 -> bf16 (memA [m][d]) + row sumsq; v -> vbf   (verified)
//  k_prepT : memA -> memTt tiled transpose image [m>>4][d][m&15]        (verified r8)
//  k_stage1: 512 WGs (256 thr, lb(256,2)) = 128 m-splits x 4 b-tiles, 16 chunks
//            of 32 m. 32x32x16 MFMA. BOTH operand images (memA for QK, memTt for
//            PV) staged to LDS via dbuf global_load_lds; PV LDS reads swizzled
//            (bit4 ^= bit8) with inverse-swizzled global source. One barrier
//            per chunk. In-lane softmax + defer-max, lane-uniform rescale,
//            register epilogue to part_o[s][dblk][b][4].
//  k_scale : per-b combine of split stats -> scale[s][b]                (verified)
//  k_out   : dblk-parallel partial reduction + epilogue                 (verified)

#define NSPLIT 128
#define NCHUNK 16

typedef __attribute__((ext_vector_type(4))) float f32x4;
typedef __attribute__((ext_vector_type(16))) float f32x16;
typedef __attribute__((ext_vector_type(8))) short s16x8;
typedef __attribute__((ext_vector_type(2))) unsigned int u32x2;
typedef __attribute__((ext_vector_type(4))) unsigned int u32x4;

__device__ __forceinline__ unsigned short bf16rn(float f) {
  unsigned x = __builtin_bit_cast(unsigned, f);
  x += 0x7fffu + ((x >> 16) & 1u);
  return (unsigned short)(x >> 16);
}
__device__ __forceinline__ unsigned pk2(float a, float b) {
  return (unsigned)bf16rn(a) | ((unsigned)bf16rn(b) << 16);
}
__device__ __forceinline__ float bf2f(unsigned short u) {
  return __builtin_bit_cast(float, ((unsigned)u) << 16);
}

// ---------------- kernel 0: prep (verified verbatim) ----------------
__global__ __launch_bounds__(512) void k_prep(const float* __restrict__ memg,
                                              const float* __restrict__ v,
                                              unsigned short* __restrict__ memA,
                                              unsigned short* __restrict__ vbf,
                                              float* __restrict__ msq) {
  const int wg = (int)blockIdx.x;
  const int tid = (int)threadIdx.x;
  const int w = tid >> 6, lane = tid & 63;
  if (wg < 256) {
    size_t m0 = (size_t)wg * 256 + w * 32;
#pragma unroll 4
    for (int i = 0; i < 32; ++i) {
      size_t m = m0 + i;
      f32x4 f = *reinterpret_cast<const f32x4*>(memg + m * 256 + lane * 4);
      u32x2 p;
      p[0] = pk2(f[0], f[1]);
      p[1] = pk2(f[2], f[3]);
      *reinterpret_cast<u32x2*>(memA + m * 256 + lane * 4) = p;
      float sq = f[0] * f[0] + f[1] * f[1] + f[2] * f[2] + f[3] * f[3];
#pragma unroll
      for (int s2 = 32; s2; s2 >>= 1) sq += __shfl_xor(sq, s2);
      if (lane == 0) msq[m] = sq;
    }
  } else {
    size_t base = (size_t)(wg - 256) * 8192 + (size_t)tid * 16;
#pragma unroll
    for (int i = 0; i < 4; ++i) {
      f32x4 f = *reinterpret_cast<const f32x4*>(v + base + i * 4);
      u32x2 p;
      p[0] = pk2(f[0], f[1]);
      p[1] = pk2(f[2], f[3]);
      *reinterpret_cast<u32x2*>(vbf + base + i * 4) = p;
    }
  }
}

// ---------------- kernel 0b: memTt[m>>4][d][m&15] (verified r8 verbatim) ----------------
__global__ __launch_bounds__(256) void k_prepT(const unsigned short* __restrict__ memA,
                                               unsigned short* __restrict__ memTt) {
  __shared__ __align__(16) char sl[32 * 528];
  const int t = (int)threadIdx.x;
  const int wg = (int)blockIdx.x;  // slab m0 = wg*32
  const int mm = t >> 3, dp = t & 7;
  const char* src = (const char*)memA + (((size_t)wg * 32 + mm) * 256 + (size_t)dp * 32) * 2;
#pragma unroll
  for (int j = 0; j < 4; ++j) {
    u32x4 vd = *reinterpret_cast<const u32x4*>(src + j * 16);
    *reinterpret_cast<u32x4*>(sl + mm * 528 + dp * 64 + j * 16) = vd;
  }
  __syncthreads();
#pragma unroll
  for (int h = 0; h < 2; ++h) {
    const int d = t;  // 0..255
    unsigned wbuf[8];
#pragma unroll
    for (int i = 0; i < 8; ++i) {
      unsigned lo = *reinterpret_cast<const unsigned short*>(sl + (h * 16 + 2 * i) * 528 + d * 2);
      unsigned hv = *reinterpret_cast<const unsigned short*>(sl + (h * 16 + 2 * i + 1) * 528 + d * 2);
      wbuf[i] = lo | (hv << 16);
    }
    char* dst = (char*)memTt + ((size_t)wg * 2 + h) * 8192 + (size_t)d * 32;
    u32x4 o0, o1;
    o0[0] = wbuf[0]; o0[1] = wbuf[1]; o0[2] = wbuf[2]; o0[3] = wbuf[3];
    o1[0] = wbuf[4]; o1[1] = wbuf[5]; o1[2] = wbuf[6]; o1[3] = wbuf[7];
    *reinterpret_cast<u32x4*>(dst) = o0;
    *reinterpret_cast<u32x4*>(dst + 16) = o1;
  }
}

// ---------------- kernel 1: split-M flash ----------------
__global__ __launch_bounds__(256, 2) void k_stage1(
    const unsigned short* __restrict__ memA, const unsigned short* __restrict__ memTt,
    const unsigned short* __restrict__ vbf, const float* __restrict__ msq,
    unsigned short* __restrict__ part_o, float* __restrict__ part_m,
    float* __restrict__ part_l) {
  __shared__ __align__(16) char lds[65536];  // Ab0 16K | Ab1 16K | Tt0 16K | Tt1 16K
  char* const Ab0 = lds;
  char* const Ab1 = lds + 16384;
  char* const Tt0 = lds + 32768;
  char* const Tt1 = lds + 49152;

  const int tid = (int)threadIdx.x;
  const int w = tid >> 6;
  const int lane = tid & 63;
  const int hi = lane >> 5;
  const int c5 = lane & 31;

  // XCD grouping: 16 splits x 4 b-tiles per XCD.
  const int bid = (int)blockIdx.x;
  const int swz = (bid & 7) * 64 + (bid >> 3);
  const int s = swz >> 2;     // m-split 0..127
  const int btile = swz & 3;  // 0..3
  const int bw = btile * 128 + w * 32;
  const int b = bw + c5;

  // QK staging source (pre-swizzled; verified r5/7/8 form)
  const char* Ac = (const char*)memA;
  const size_t qsrc = (size_t)s * 262144 + (size_t)(tid >> 5) * 512 +
                      (size_t)(((tid & 31) ^ (tid >> 5)) * 16);
  // PV staging source: LDS linear, source carries the read-swizzle involution
  // f(x) = x ^ ((bit8(x))<<4); bit8(z) = lane bit4 -> offset (lane*16)^(lane&16).
  const char* Tc = (const char*)memTt;
  const size_t tsrc = (size_t)s * 262144 + (size_t)w * 1024 +
                      (size_t)(((unsigned)lane * 16u) ^ ((unsigned)lane & 16u));

#define STAGE_A(bufp, t_)                                                        \
  do {                                                                           \
    _Pragma("unroll") for (int i_ = 0; i_ < 4; ++i_) {                           \
      __builtin_amdgcn_global_load_lds(                                          \
          (const __attribute__((address_space(1))) void*)(Ac + qsrc +            \
              (size_t)(t_) * 16384 + (size_t)i_ * 4096),                         \
          (__attribute__((address_space(3))) void*)((bufp) + w * 1024 + i_ * 4096), \
          16, 0, 0);                                                             \
    }                                                                            \
  } while (0)
#define STAGE_T(bufp, t_)                                                        \
  do {                                                                           \
    _Pragma("unroll") for (int i_ = 0; i_ < 4; ++i_) {                           \
      __builtin_amdgcn_global_load_lds(                                          \
          (const __attribute__((address_space(1))) void*)(Tc + tsrc +            \
              (size_t)(t_) * 16384 + (size_t)i_ * 4096),                         \
          (__attribute__((address_space(3))) void*)((bufp) + w * 1024 + i_ * 4096), \
          16, 0, 0);                                                             \
    }                                                                            \
  } while (0)

  f32x16 acc[8];
#pragma unroll
  for (int n = 0; n < 8; ++n) acc[n] = (f32x16)0.0f;
  float rm = -__builtin_inff(), rs = 0.f;

  // v B-fragments: lane holds v[b][k*16 + hi*8 .. +7] for 16 ksteps
  s16x8 vr[16];
  STAGE_A(Ab0, 0);
  STAGE_T(Tt0, 0);
#pragma unroll
  for (int k = 0; k < 16; ++k)
    vr[k] = *reinterpret_cast<const s16x8*>(vbf + (size_t)b * 256 + k * 16 + hi * 8);

  asm volatile("s_waitcnt vmcnt(0)" ::: "memory");
  __builtin_amdgcn_s_barrier();
  asm volatile("" ::: "memory");

  for (int t = 0; t < NCHUNK; ++t) {
    char* Abc = (t & 1) ? Ab1 : Ab0;
    char* Abn = (t & 1) ? Ab0 : Ab1;
    char* Ttc = (t & 1) ? Tt1 : Tt0;
    char* Ttn = (t & 1) ? Tt0 : Tt1;
    if (t < NCHUNK - 1) {
      STAGE_A(Abn, t + 1);
      STAGE_T(Ttn, t + 1);
    }

    // ---- QK^T: S[32m][32b], two accumulation chains ----
    const char* qb = Abc + c5 * 512;
    f32x16 Sa = (f32x16)0.0f, Sb = (f32x16)0.0f;
    __builtin_amdgcn_s_setprio(1);
#pragma unroll
    for (int k = 0; k < 16; k += 2) {
      s16x8 a0 = *reinterpret_cast<const s16x8*>(qb + ((k * 32 + hi * 16) ^ ((c5 & 7) << 4)));
      s16x8 a1 = *reinterpret_cast<const s16x8*>(qb + (((k + 1) * 32 + hi * 16) ^ ((c5 & 7) << 4)));
      Sa = __builtin_amdgcn_mfma_f32_32x32x16_bf16(a0, vr[k], Sa, 0, 0, 0);
      Sb = __builtin_amdgcn_mfma_f32_32x32x16_bf16(a1, vr[k + 1], Sb, 0, 0, 0);
    }
    __builtin_amdgcn_s_setprio(0);
    f32x16 S = Sa + Sb;

    // ---- bias: S row m = (reg&3) + 8*(reg>>2) + 4*hi ----
    const int mc = s * 512 + t * 32;
#pragma unroll
    for (int q = 0; q < 4; ++q) {
      f32x4 qq = *reinterpret_cast<const f32x4*>(msq + mc + 8 * q + 4 * hi);
#pragma unroll
      for (int r = 0; r < 4; ++r) S[4 * q + r] -= 0.5f * qq[r];
    }

    // ---- in-lane online softmax (col b = bw + c5), defer-max THR=8 ----
    float mx = S[0];
#pragma unroll
    for (int i = 1; i < 16; ++i) mx = fmaxf(mx, S[i]);
    mx = fmaxf(mx, __shfl_xor(mx, 32));
    if (!__all(mx <= rm + 8.0f)) {
      float nm = fmaxf(rm, mx);
      float al = __expf(rm - nm);
      rm = nm;
      rs *= al;
#pragma unroll
      for (int n = 0; n < 8; ++n) acc[n] *= al;
    }
    float ls = 0.f;
#pragma unroll
    for (int i = 0; i < 16; ++i) {
      float p = __expf(S[i] - rm);
      S[i] = p;
      ls += p;
    }
    ls += __shfl_xor(ls, 32);
    rs += ls;

    // ---- P -> B-fragments (verified lane shuffle) ----
    unsigned pkd[8];
#pragma unroll
    for (int p = 0; p < 8; ++p) pkd[p] = pk2(S[2 * p], S[2 * p + 1]);
    s16x8 pb0, pb1;
#pragma unroll
    for (int kk = 0; kk < 2; ++kk) {
      u32x4 wv;
#pragma unroll
      for (int i = 0; i < 4; ++i) {
        const int src = (i >> 1) * 32 + c5;
        unsigned lo = (unsigned)__shfl((int)pkd[(i & 1) + 4 * kk], src);
        unsigned hv = (unsigned)__shfl((int)pkd[(i & 1) + 4 * kk + 2], src);
        wv[i] = hi ? hv : lo;
      }
      if (kk == 0) pb0 = __builtin_bit_cast(s16x8, wv);
      else         pb1 = __builtin_bit_cast(s16x8, wv);
    }

    // ---- PV: acc[d][b] += memT @ P (A = LDS Tt, swizzled reads) ----
    __builtin_amdgcn_s_setprio(1);
#pragma unroll
    for (int n = 0; n < 8; ++n) {
      const int ro = n * 1024 + c5 * 32 + ((hi * 16) ^ ((c5 & 8) << 1));
      s16x8 bm0 = *reinterpret_cast<const s16x8*>(Ttc + ro);
      s16x8 bm1 = *reinterpret_cast<const s16x8*>(Ttc + ro + 8192);
      acc[n] = __builtin_amdgcn_mfma_f32_32x32x16_bf16(bm0, pb0, acc[n], 0, 0, 0);
      acc[n] = __builtin_amdgcn_mfma_f32_32x32x16_bf16(bm1, pb1, acc[n], 0, 0, 0);
    }
    __builtin_amdgcn_s_setprio(0);

    asm volatile("s_waitcnt vmcnt(0)" ::: "memory");
    __builtin_amdgcn_s_barrier();
    asm volatile("" ::: "memory");
  }

  // ---- stats [s][b] ----
  if (hi == 0) {
    part_m[(size_t)s * 512 + b] = rm;
    part_l[(size_t)s * 512 + b] = rs;
  }

  // ---- epilogue: direct coalesced stores, part_o[s][dblk(64)][b(512)][4] ----
  // acc lane layout: b = bw + c5, d = n*32 + 8q + 4hi + r  ->  dblk = n*8 + 2q + hi
#pragma unroll
  for (int n = 0; n < 8; ++n) {
#pragma unroll
    for (int q = 0; q < 4; ++q) {
      u32x2 pw;
      pw[0] = pk2(acc[n][4 * q + 0], acc[n][4 * q + 1]);
      pw[1] = pk2(acc[n][4 * q + 2], acc[n][4 * q + 3]);
      *reinterpret_cast<u32x2*>(part_o + (size_t)s * 131072 +
                                (size_t)(n * 8 + 2 * q + hi) * 2048 + (size_t)b * 4) = pw;
    }
  }
#undef STAGE_A
#undef STAGE_T
}

// ---------------- kernel 2: per-b stat combine -> scale[s][b] (verified) ----------------
__global__ __launch_bounds__(128) void k_scale(const float* __restrict__ part_m,
                                               const float* __restrict__ part_l,
                                               float* __restrict__ scale) {
  const int b = (int)blockIdx.x, t = (int)threadIdx.x;
  const int wv = t >> 6;
  __shared__ float red[4];
  float m = part_m[(size_t)t * 512 + b];
  float l = part_l[(size_t)t * 512 + b];
  float mm = m;
#pragma unroll
  for (int s2 = 32; s2; s2 >>= 1) mm = fmaxf(mm, __shfl_xor(mm, s2));
  if ((t & 63) == 0) red[wv] = mm;
  __syncthreads();
  float M = fmaxf(red[0], red[1]);
  float e = __expf(m - M);
  float z = e * l;
#pragma unroll
  for (int s2 = 32; s2; s2 >>= 1) z += __shfl_xor(z, s2);
  if ((t & 63) == 0) red[2 + wv] = z;
  __syncthreads();
  float Z = red[2] + red[3];
  scale[(size_t)t * 512 + b] = e / Z;
}

// ---------------- kernel 3: reduce partials + epilogue (verified) ----------------
__global__ __launch_bounds__(128) void k_out(const unsigned short* __restrict__ part_o,
                                             const float* __restrict__ scale,
                                             const float* __restrict__ v,
                                             const float* __restrict__ mask,
                                             float* __restrict__ out) {
  const int dblk = (int)blockIdx.x >> 2;                         // 0..63
  const int b = ((int)blockIdx.x & 3) * 128 + (int)threadIdx.x;  // 0..511
  float a0 = 0.f, a1 = 0.f, a2 = 0.f, a3 = 0.f;
  const unsigned short* po = part_o + (size_t)dblk * 2048 + (size_t)b * 4;
#pragma unroll 8
  for (int gi = 0; gi < NSPLIT; ++gi) {
    u32x2 pw = *reinterpret_cast<const u32x2*>(po + (size_t)gi * 131072);
    float sc = scale[(size_t)gi * 512 + b];
    a0 = fmaf(sc, bf2f((unsigned short)pw[0]), a0);
    a1 = fmaf(sc, bf2f((unsigned short)(pw[0] >> 16)), a1);
    a2 = fmaf(sc, bf2f((unsigned short)pw[1]), a2);
    a3 = fmaf(sc, bf2f((unsigned short)(pw[1] >> 16)), a3);
  }
  const size_t idx = (size_t)b * 256 + (size_t)dblk * 4;
  f32x4 vv = *reinterpret_cast<const f32x4*>(v + idx);
  f32x4 mk = *reinterpret_cast<const f32x4*>(mask + idx);
  f32x4 o;
  o[0] = vv[0] + 0.5f * (a0 - vv[0]) * mk[0];
  o[1] = vv[1] + 0.5f * (a1 - vv[1]) * mk[1];
  o[2] = vv[2] + 0.5f * (a2 - vv[2]) * mk[2];
  o[3] = vv[3] + 0.5f * (a3 - vv[3]) * mk[3];
  *reinterpret_cast<f32x4*>(out + idx) = o;
}

extern "C" void kernel_launch(void* const* d_in, const int* in_sizes, int n_in,
                              void* d_out, int out_size, void* d_ws, size_t ws_size,
                              hipStream_t stream) {
  const float* v = (const float*)d_in[0];       // [512,256]
  const float* mask = (const float*)d_in[1];    // [512,256]
  const float* memg = (const float*)d_in[2];    // [65536,256]
  float* out = (float*)d_out;

  char* ws = (char*)d_ws;
  const size_t SZ_PO = (size_t)NSPLIT * 64 * 512 * 4 * 2;  // 32 MiB  [s][dblk][b][4] u16
  const size_t SZ_MA = (size_t)65536 * 256 * 2;            // 32 MiB
  const size_t SZ_MS = (size_t)65536 * 4;                  // 256 KiB
  const size_t SZ_VB = (size_t)512 * 256 * 2;              // 256 KiB
  const size_t SZ_ST = (size_t)NSPLIT * 512 * 4;           // 256 KiB
  unsigned short* part_o = (unsigned short*)ws;
  unsigned short* memA = (unsigned short*)(ws + SZ_PO);
  float* msq = (float*)(ws + SZ_PO + SZ_MA);
  unsigned short* vbf = (unsigned short*)(ws + SZ_PO + SZ_MA + SZ_MS);
  float* part_m = (float*)(ws + SZ_PO + SZ_MA + SZ_MS + SZ_VB);
  float* part_l = (float*)(ws + SZ_PO + SZ_MA + SZ_MS + SZ_VB + SZ_ST);
  float* scale = (float*)(ws + SZ_PO + SZ_MA + SZ_MS + SZ_VB + 2 * SZ_ST);
  unsigned short* memTt = (unsigned short*)(ws + SZ_PO + SZ_MA + SZ_MS + SZ_VB + 3 * SZ_ST);

  k_prep<<<dim3(272), dim3(512), 0, stream>>>(memg, v, memA, vbf, msq);
  k_prepT<<<dim3(2048), dim3(256), 0, stream>>>(memA, memTt);
  k_stage1<<<dim3(512), dim3(256), 0, stream>>>(memA, memTt, vbf, msq, part_o, part_m, part_l);
  k_scale<<<dim3(512), dim3(128), 0, stream>>>(part_m, part_l, scale);
  k_out<<<dim3(256), dim3(128), 0, stream>>>(part_o, scale, v, mask, out);
}